// Round 7
// baseline (217.989 us; speedup 1.0000x reference)
//
#include <hip/hip_runtime.h>

// ---------------------------------------------------------------------------
// Round 11: k6 software pipeline (only change):
//   - G tiles via global_load_lds (async, pre-swizzled source, no VGPR trip)
//   - X transpose: register prefetch one chunk ahead (issue before MFMA,
//     LDS-write after barrier) -> HBM latency hidden under MFMA
//   - __launch_bounds__(256,4) pins VGPR<=128 for 4 blocks/CU
//   k0/k1/k1r/k3ab/k5b unchanged.
// ---------------------------------------------------------------------------

constexpr int kB = 4;
constexpr int kC = 256;
constexpr int kHW = 16384;
constexpr int kHeads = 64;
constexpr int kNG = 32;
constexpr int kCPG = 8;
constexpr int kCP1 = 257;
constexpr int kPS = 260;          // padded row stride (floats) for S
constexpr float kEPS = 1e-5f;
constexpr int kNSplit = 32;       // syrk K-splits

typedef __attribute__((ext_vector_type(8))) _Float16 f16x8;
typedef __attribute__((ext_vector_type(4))) _Float16 f16x4;
typedef __attribute__((ext_vector_type(4))) float f32x4;

union V8 { f16x8 v; uint4 u; _Float16 h[8]; };

// async global->LDS, 16B per lane; lds ptr must be wave-uniform.
__device__ __forceinline__ void gload16(const void* g, void* l) {
  __builtin_amdgcn_global_load_lds(
      (const __attribute__((address_space(1))) void*)g,
      (__attribute__((address_space(3))) void*)l, 16, 0, 0);
}

// workspace layout (float-unit offsets)
constexpr size_t oXH    = 0;                                    // fp16 xH [b][c][n]
constexpr size_t oSpart = oXH + (size_t)kB * kHW * kC / 2;      // 3*B*kNSplit*128*128
constexpr size_t oS     = oSpart + (size_t)3 * kB * kNSplit * 128 * 128;
constexpr size_t oSums  = oS + (size_t)kB * kCP1 * kPS;         // B x 256 row sums
constexpr size_t oGv    = oSums + (size_t)kB * kC;              // adjacent (one memset)
constexpr size_t oScore = oGv + (size_t)kB * kC;
constexpr size_t oGmH   = oScore + (size_t)kB * kHeads * 16;    // fp16 B x 256 x 256

// ---------------------------------------------------------------------------
// K0: streaming cast x -> xH (fp16, same layout) + fp32 row sums.
// ---------------------------------------------------------------------------
__global__ __launch_bounds__(256) void k0_cast(const float* __restrict__ x,
                                               _Float16* __restrict__ xH,
                                               float* __restrict__ sums) {
  const int seg = blockIdx.x, c = blockIdx.y, b = blockIdx.z;
  const int tid = threadIdx.x;
  const size_t base = ((size_t)b * kC + c) * kHW + (size_t)seg * 4096 + tid * 16;
  float4 v0 = *(const float4*)(x + base);
  float4 v1 = *(const float4*)(x + base + 4);
  float4 v2 = *(const float4*)(x + base + 8);
  float4 v3 = *(const float4*)(x + base + 12);
  V8 h0, h1;
  h0.h[0] = (_Float16)v0.x; h0.h[1] = (_Float16)v0.y;
  h0.h[2] = (_Float16)v0.z; h0.h[3] = (_Float16)v0.w;
  h0.h[4] = (_Float16)v1.x; h0.h[5] = (_Float16)v1.y;
  h0.h[6] = (_Float16)v1.z; h0.h[7] = (_Float16)v1.w;
  h1.h[0] = (_Float16)v2.x; h1.h[1] = (_Float16)v2.y;
  h1.h[2] = (_Float16)v2.z; h1.h[3] = (_Float16)v2.w;
  h1.h[4] = (_Float16)v3.x; h1.h[5] = (_Float16)v3.y;
  h1.h[6] = (_Float16)v3.z; h1.h[7] = (_Float16)v3.w;
  *(uint4*)(xH + base) = h0.u;
  *(uint4*)(xH + base + 8) = h1.u;
  float rs = (v0.x + v0.y + v0.z + v0.w) + (v1.x + v1.y + v1.z + v1.w) +
             (v2.x + v2.y + v2.z + v2.w) + (v3.x + v3.y + v3.z + v3.w);
#pragma unroll
  for (int off = 32; off; off >>= 1) rs += __shfl_xor(rs, off);
  __shared__ float ps[4];
  if ((tid & 63) == 0) ps[tid >> 6] = rs;
  __syncthreads();
  if (tid == 0) atomicAdd(&sums[b * kC + c], ps[0] + ps[1] + ps[2] + ps[3]);
}

// ---------------------------------------------------------------------------
// K1: MFMA syrk reading xH. Tiles (0,0),(0,1),(1,1) of 128x128; 32 K-splits.
// grid (96, B), 256 thr. XCD-pairing block remap.
// ---------------------------------------------------------------------------
__global__ __launch_bounds__(256) void k1_syrk(const _Float16* __restrict__ xH,
                                               float* __restrict__ Spart) {
  const int bx = blockIdx.x;
  const int chunk = bx / 24, rr0 = bx % 24;
  const int tt = rr0 >> 3;               // 0..2
  const int sp = chunk * 8 + (rr0 & 7);  // 0..31
  const int b = blockIdx.y;
  const int ti = (tt == 2) ? 1 : 0;
  const int tj = (tt == 0) ? 0 : 1;
  const bool diag = (ti == tj);
  const _Float16* xb = xH + (size_t)b * kC * kHW;
  const int n0 = sp * (kHW / kNSplit);   // 512 per split

  __shared__ __align__(16) _Float16 XI[2][128 * 64];   // 2 x 16 KB
  __shared__ __align__(16) _Float16 XJ[2][128 * 64];   // 2 x 16 KB

  const int tid = threadIdx.x;
  const int wave = tid >> 6, lane = tid & 63;
  const int wi = wave >> 1, wj = wave & 1;
  const int lrow = lane & 15, lgq = lane >> 4;
  const int srow = lane >> 3, sslot = lane & 7;

  const _Float16* srcI = xb + (size_t)(ti * 128) * kHW + n0;
  const _Float16* srcJ = xb + (size_t)(tj * 128) * kHW + n0;

  f32x4 acc[16];
#pragma unroll
  for (int i = 0; i < 16; ++i) acc[i] = (f32x4){0.f, 0.f, 0.f, 0.f};

  auto stage = [&](int buf, int nb) {
#pragma unroll
    for (int rep = 0; rep < 4; ++rep) {
      const int rr = rep * 32 + wave * 8 + srow;
      const int g = sslot ^ (rr & 7);
      char* dI = (char*)XI[buf] + (rep * 32 + wave * 8) * 128;   // wave-uniform
      gload16(srcI + (size_t)rr * kHW + nb + g * 8, dI);
      if (!diag) {
        char* dJ = (char*)XJ[buf] + (rep * 32 + wave * 8) * 128;
        gload16(srcJ + (size_t)rr * kHW + nb + g * 8, dJ);
      }
    }
  };

  stage(0, 0);
  __syncthreads();   // drains vmcnt(0): buf0 ready

  constexpr int NCH = kHW / kNSplit / 64;   // 8
  for (int ch = 0; ch < NCH; ++ch) {
    const int buf = ch & 1;
    if (ch + 1 < NCH) stage(buf ^ 1, (ch + 1) * 64);   // prefetch next chunk
    const _Float16* XIb = XI[buf];
    const _Float16* XBb = diag ? XI[buf] : XJ[buf];
#pragma unroll
    for (int sub = 0; sub < 2; ++sub) {
      const int gq = sub * 4 + lgq;
      f16x8 afr[4], bfr[4];
#pragma unroll
      for (int ia = 0; ia < 4; ++ia) {
        const int r = wi * 64 + ia * 16 + lrow;
        afr[ia] = *(const f16x8*)((const char*)XIb + (size_t)r * 128 + (((unsigned)(gq ^ (r & 7))) << 4));
      }
#pragma unroll
      for (int jb = 0; jb < 4; ++jb) {
        const int r = wj * 64 + jb * 16 + lrow;
        bfr[jb] = *(const f16x8*)((const char*)XBb + (size_t)r * 128 + (((unsigned)(gq ^ (r & 7))) << 4));
      }
#pragma unroll
      for (int ia = 0; ia < 4; ++ia)
#pragma unroll
        for (int jb = 0; jb < 4; ++jb)
          acc[ia * 4 + jb] = __builtin_amdgcn_mfma_f32_16x16x32_f16(afr[ia], bfr[jb], acc[ia * 4 + jb], 0, 0, 0);
    }
    __syncthreads();   // drains prefetch vmcnt + LDS reads; buf^1 ready
  }
  float* P = Spart + (((size_t)tt * kB + b) * kNSplit + sp) * 16384;
#pragma unroll
  for (int ia = 0; ia < 4; ++ia)
#pragma unroll
    for (int jb = 0; jb < 4; ++jb)
#pragma unroll
      for (int reg = 0; reg < 4; ++reg) {
        const int i = wi * 64 + ia * 16 + lgq * 4 + reg;
        const int j = wj * 64 + jb * 16 + lrow;
        P[(size_t)i * 128 + j] = acc[ia * 4 + jb][reg];
      }
}

// ---------------------------------------------------------------------------
// K1r: reduce split partials -> full symmetric padded S (stride kPS).
// ---------------------------------------------------------------------------
__global__ __launch_bounds__(256) void k1r_reduce(const float* __restrict__ Spart,
                                                  float* __restrict__ S) {
  const int blk = blockIdx.x;
  const int tile12 = blk >> 5;          // 0..11
  const int part = blk & 31;
  const int tt = tile12 >> 2, b = tile12 & 3;
  const int rti = (tt == 2) ? 1 : 0;
  const int rtj = (tt == 0) ? 0 : 1;
  const int e0 = part * 512 + threadIdx.x * 2;
  float2 s = {0.f, 0.f};
  const float* base = Spart + ((size_t)tt * kB + b) * kNSplit * 16384 + e0;
#pragma unroll 8
  for (int sp = 0; sp < kNSplit; ++sp) {
    float2 v = *(const float2*)(base + (size_t)sp * 16384);
    s.x += v.x; s.y += v.y;
  }
  const int i = e0 >> 7, j = e0 & 127;
  float* Sb = S + (size_t)b * kCP1 * kPS;
  float* dst = Sb + (size_t)(rti * 128 + i) * kPS + rtj * 128 + j;
  dst[0] = s.x; dst[1] = s.y;
  if (tt == 1) {  // mirror into lower triangle
    Sb[(size_t)(128 + j + 0) * kPS + i] = s.x;
    Sb[(size_t)(128 + j + 1) * kPS + i] = s.y;
  }
}

// ---------------------------------------------------------------------------
// K3ab: scores directly from S (fused k3a+k3b); GN stats inline.
// ---------------------------------------------------------------------------
__global__ __launch_bounds__(256) void k3ab(const float* __restrict__ S,
                                            const float* __restrict__ sums,
                                            const float* __restrict__ gw,
                                            const float* __restrict__ gb,
                                            const float* __restrict__ qkv_w,
                                            const float* __restrict__ qkv_b,
                                            float* __restrict__ score) {
  const int h = blockIdx.x, b = blockIdx.y;
  const float* Sb = S + (size_t)b * kCP1 * kPS;
  const float HWf = (float)kHW;
  __shared__ float shx[kC], shd[kC];
  __shared__ float meanv[kNG], invv[kNG];
  __shared__ float4 suw[kC];
  __shared__ float redPQ[4][8];
  __shared__ float red16[4][16];
  const int tid = threadIdx.x;
  const int wave = tid >> 6, lane = tid & 63;

  shx[tid] = sums[b * kC + tid];
  shd[tid] = Sb[(size_t)tid * kPS + tid];
  __syncthreads();
  if (tid < kNG) {
    float sum = 0.f, ssq = 0.f;
#pragma unroll
    for (int k = 0; k < kCPG; ++k) { sum += shx[tid * kCPG + k]; ssq += shd[tid * kCPG + k]; }
    const float n = (float)(kCPG * kHW);
    const float mean = sum / n;
    const float var = (ssq - n * mean * mean) / (n - 1.0f);  // ddof=1
    meanv[tid] = mean;
    invv[tid] = rsqrtf(var + kEPS);
  }
  __syncthreads();
  const float s_c = gw[tid] * invv[tid / kCPG];
  const float t_c = gb[tid] - meanv[tid / kCPG] * s_c;
  const float x_c = shx[tid];
  const float r_c = s_c * x_c + t_c * HWf;

  const float u0 = qkv_w[(size_t)(h * 12 + 0) * kC + tid];
  const float u1 = qkv_w[(size_t)(h * 12 + 1) * kC + tid];
  const float u2 = qkv_w[(size_t)(h * 12 + 2) * kC + tid];
  const float u3 = qkv_w[(size_t)(h * 12 + 3) * kC + tid];
  const float v0 = qkv_w[(size_t)(h * 12 + 4) * kC + tid];
  const float v1 = qkv_w[(size_t)(h * 12 + 5) * kC + tid];
  const float v2 = qkv_w[(size_t)(h * 12 + 6) * kC + tid];
  const float v3 = qkv_w[(size_t)(h * 12 + 7) * kC + tid];
  suw[tid] = make_float4(u0 * s_c, u1 * s_c, u2 * s_c, u3 * s_c);

  float p[8] = {u0 * s_c * x_c, u1 * s_c * x_c, u2 * s_c * x_c, u3 * s_c * x_c,
                u0 * t_c, u1 * t_c, u2 * t_c, u3 * t_c};
#pragma unroll
  for (int i = 0; i < 8; ++i)
#pragma unroll
    for (int off = 32; off; off >>= 1) p[i] += __shfl_xor(p[i], off);
  if (lane == 0) {
#pragma unroll
    for (int i = 0; i < 8; ++i) redPQ[wave][i] = p[i];
  }
  __syncthreads();
  float P[4], Qp[4];
#pragma unroll
  for (int d = 0; d < 4; ++d) {
    P[d]  = redPQ[0][d] + redPQ[1][d] + redPQ[2][d] + redPQ[3][d];
    Qp[d] = redPQ[0][4 + d] + redPQ[1][4 + d] + redPQ[2][4 + d] + redPQ[3][4 + d]
            + qkv_b[h * 12 + d];
  }

  float sd0 = 0.f, sd1 = 0.f, sd2 = 0.f, sd3 = 0.f;
#pragma unroll 8
  for (int c = 0; c < kC; ++c) {
    const float Sval = Sb[(size_t)c * kPS + tid];
    const float4 w = suw[c];
    sd0 += w.x * Sval; sd1 += w.y * Sval; sd2 += w.z * Sval; sd3 += w.w * Sval;
  }
  float wd[4];
#pragma unroll
  for (int d = 0; d < 4; ++d) {
    const float sdv = (d == 0) ? sd0 : (d == 1) ? sd1 : (d == 2) ? sd2 : sd3;
    wd[d] = s_c * sdv + t_c * P[d] + r_c * Qp[d];
  }
  const float sv[4] = {v0, v1, v2, v3};
  float pr[16];
#pragma unroll
  for (int d = 0; d < 4; ++d)
#pragma unroll
    for (int e = 0; e < 4; ++e) pr[d * 4 + e] = wd[d] * sv[e];
#pragma unroll
  for (int i = 0; i < 16; ++i)
#pragma unroll
    for (int off = 32; off; off >>= 1) pr[i] += __shfl_xor(pr[i], off);
  if (lane == 0) {
#pragma unroll
    for (int i = 0; i < 16; ++i) red16[wave][i] = pr[i];
  }
  __syncthreads();
  if (tid < 16) {
    const int d = tid >> 2, e = tid & 3;
    float tot = red16[0][tid] + red16[1][tid] + red16[2][tid] + red16[3][tid];
    const float w256 = P[d] + HWf * Qp[d];
    tot += w256 * qkv_b[h * 12 + 4 + e];
    score[((size_t)(b * kHeads) + h) * 16 + tid] = 0.5f * tot;
  }
}

// ---------------------------------------------------------------------------
// K5b (k45 fused): softmax over heads in-block, M synthesized during staging
// as rank-4 mix of Wv rows; F = out_w @ M'; emit G fp16 + gvec atomics.
// ---------------------------------------------------------------------------
__global__ __launch_bounds__(256) void k5b_gemm(const float* __restrict__ out_w,
                                                const float* __restrict__ S,
                                                const float* __restrict__ sums,
                                                const float* __restrict__ gw,
                                                const float* __restrict__ gb,
                                                const float* __restrict__ score,
                                                const float* __restrict__ qkv_w,
                                                const float* __restrict__ qkv_b,
                                                _Float16* __restrict__ GmH,
                                                float* __restrict__ gvec) {
  const int ct = blockIdx.x, ot = blockIdx.y, b = blockIdx.z;
  const float* Sb = S + (size_t)b * kCP1 * kPS;
  __shared__ float Wt[32][68];
  __shared__ float Gs[32][68];
  __shared__ float gred[64][17];
  __shared__ float sS[kC], sT[kC];
  __shared__ float meanv[kNG], invv[kNG];
  __shared__ float scs[kHeads * 16];     // 4 KB scores
  __shared__ float pw[kC][4];            // softmax weights per cidx
  __shared__ float mxp[16], smp[16];
  __shared__ float wred[4][16];
  const int tid = threadIdx.x;
  const int wave = tid >> 6, lane = tid & 63;

  sS[tid] = sums[b * kC + tid];
  sT[tid] = Sb[(size_t)tid * kPS + tid];        // diag (temp)
  *(float4*)&scs[tid * 4] = ((const float4*)(score + (size_t)b * kHeads * 16))[tid];
  __syncthreads();
  if (tid < kNG) {
    float sum = 0.f, ssq = 0.f;
#pragma unroll
    for (int k = 0; k < kCPG; ++k) { sum += sS[tid * kCPG + k]; ssq += sT[tid * kCPG + k]; }
    const float n = (float)(kCPG * kHW);
    const float mean = sum / n;
    const float var = (ssq - n * mean * mean) / (n - 1.0f);
    meanv[tid] = mean;
    invv[tid] = rsqrtf(var + kEPS);
  }
  {
    const int p = tid & 15, hh = tid >> 4;
    float m = scs[(hh * 4 + 0) * 16 + p];
#pragma unroll
    for (int k = 1; k < 4; ++k) m = fmaxf(m, scs[(hh * 4 + k) * 16 + p]);
    m = fmaxf(m, __shfl_xor(m, 16));
    m = fmaxf(m, __shfl_xor(m, 32));
    if (lane < 16) wred[wave][lane] = m;
  }
  __syncthreads();
  if (tid < 16) mxp[tid] = fmaxf(fmaxf(wred[0][tid], wred[1][tid]),
                                 fmaxf(wred[2][tid], wred[3][tid]));
  __syncthreads();
  {
    const int p = tid & 15, hh = tid >> 4;
    float s = 0.f;
#pragma unroll
    for (int k = 0; k < 4; ++k) s += expf(scs[(hh * 4 + k) * 16 + p] - mxp[p]);
    s += __shfl_xor(s, 16);
    s += __shfl_xor(s, 32);
    if (lane < 16) wred[wave][lane] = s;
  }
  __syncthreads();
  if (tid < 16) smp[tid] = wred[0][tid] + wred[1][tid] + wred[2][tid] + wred[3][tid];
  __syncthreads();
  {
    const int h = tid >> 2, d = tid & 3;
#pragma unroll
    for (int e = 0; e < 4; ++e)
      pw[tid][e] = expf(scs[h * 16 + d * 4 + e] - mxp[d * 4 + e]) / smp[d * 4 + e];
    const float sv = gw[tid] * invv[tid / kCPG];
    sS[tid] = sv;
    sT[tid] = gb[tid] - meanv[tid / kCPG] * sv;
  }
  __syncthreads();

  float acc[16];
#pragma unroll
  for (int i = 0; i < 16; ++i) acc[i] = 0.f;
  const int i0 = (tid & 15) * 4;
  const int j0 = (tid >> 4) * 4;
  const int cp0 = ct * 64;

  for (int cb = 0; cb < kC; cb += 32) {
    int idx = tid;
#pragma unroll
    for (int r = 0; r < 2; ++r) {
      const int m = idx >> 3;
      const int c4 = (idx & 7) * 4;
      float4 v = *(const float4*)(out_w + (size_t)(ot * 64 + m) * kC + cb + c4);
      Wt[c4 + 0][m] = v.x; Wt[c4 + 1][m] = v.y; Wt[c4 + 2][m] = v.z; Wt[c4 + 3][m] = v.w;
      idx += 256;
    }
    idx = tid;
#pragma unroll
    for (int r = 0; r < 2; ++r) {
      const int cc = idx >> 4;
      const int n4 = (idx & 15) * 4;
      const int cidx = cb + cc;
      const int h = cidx >> 2;
      const float4 pv = *(const float4*)&pw[cidx][0];
      const int cp = cp0 + n4;
      float4 o;
      if (cp < kC) {
        const float* w0 = qkv_w + (size_t)(h * 12 + 8) * kC + cp;
        const float4 a0 = *(const float4*)(w0);
        const float4 a1 = *(const float4*)(w0 + kC);
        const float4 a2 = *(const float4*)(w0 + 2 * kC);
        const float4 a3 = *(const float4*)(w0 + 3 * kC);
        o.x = pv.x * a0.x + pv.y * a1.x + pv.z * a2.x + pv.w * a3.x;
        o.y = pv.x * a0.y + pv.y * a1.y + pv.z * a2.y + pv.w * a3.y;
        o.z = pv.x * a0.z + pv.y * a1.z + pv.z * a2.z + pv.w * a3.z;
        o.w = pv.x * a0.w + pv.y * a1.w + pv.z * a2.w + pv.w * a3.w;
      } else if (cp == kC) {
        const float bs = pv.x * qkv_b[h * 12 + 8] + pv.y * qkv_b[h * 12 + 9] +
                         pv.z * qkv_b[h * 12 + 10] + pv.w * qkv_b[h * 12 + 11];
        o = (float4){bs, 0.f, 0.f, 0.f};
      } else {
        o = (float4){0.f, 0.f, 0.f, 0.f};
      }
      *(float4*)&Gs[cc][n4] = o;
      idx += 256;
    }
    __syncthreads();
#pragma unroll
    for (int kk = 0; kk < 32; ++kk) {
      float4 a = *(const float4*)&Wt[kk][i0];
      float4 g = *(const float4*)&Gs[kk][j0];
      acc[0]  += a.x * g.x; acc[1]  += a.x * g.y; acc[2]  += a.x * g.z; acc[3]  += a.x * g.w;
      acc[4]  += a.y * g.x; acc[5]  += a.y * g.y; acc[6]  += a.y * g.z; acc[7]  += a.y * g.w;
      acc[8]  += a.z * g.x; acc[9]  += a.z * g.y; acc[10] += a.z * g.z; acc[11] += a.z * g.w;
      acc[12] += a.w * g.x; acc[13] += a.w * g.y; acc[14] += a.w * g.z; acc[15] += a.w * g.w;
    }
    __syncthreads();
  }
  float gpart[4] = {0.f, 0.f, 0.f, 0.f};
#pragma unroll
  for (int mi = 0; mi < 4; ++mi) {
    const int o = ot * 64 + i0 + mi;
#pragma unroll
    for (int cj = 0; cj < 4; ++cj) {
      const int cp = cp0 + j0 + cj;
      const float f = acc[mi * 4 + cj];
      if (cp < kC) {
        GmH[((size_t)b * kC + o) * kC + cp] = (_Float16)(f * sS[cp]);
        gpart[mi] += f * sT[cp];
      } else if (cp == kC) {
        gpart[mi] += f;
      }
    }
  }
#pragma unroll
  for (int mi = 0; mi < 4; ++mi) gred[i0 + mi][tid >> 4] = gpart[mi];
  __syncthreads();
  if (tid < 64) {
    float s = 0.f;
#pragma unroll
    for (int k = 0; k < 16; ++k) s += gred[tid][k];
    atomicAdd(&gvec[b * kC + ot * 64 + tid], s);
  }
}

// ---------------------------------------------------------------------------
// K6: out = G @ X + (g + out_b) + skip via MFMA; coalesced LDS epilogue.
// Pipelined: G via global_load_lds (pre-swizzled source), X register
// prefetch one chunk ahead (issue before MFMA, LDS-write after barrier).
// grid (HW/128, C/128, B), 256 thr, 33.8 KB LDS, VGPR pinned <=128.
// ---------------------------------------------------------------------------
__global__ __launch_bounds__(256, 4) void k6_final(const _Float16* __restrict__ xH,
                                                   const _Float16* __restrict__ GmH,
                                                   const float* __restrict__ gvec,
                                                   const float* __restrict__ out_b,
                                                   const float* __restrict__ x,
                                                   float* __restrict__ out) {
  const int nt = blockIdx.x, ot = blockIdx.y, b = blockIdx.z;
  __shared__ __align__(16) char smem[64 * 132 * 4];   // 33792 B; aliased below
  _Float16* GT = (_Float16*)smem;                     // 16 KB
  _Float16* XT = (_Float16*)(smem + 16384);           // 16 KB
  float* Ep = (float*)smem;                           // epilogue 64 x 132 fp32
  const int tid = threadIdx.x;
  const int wave = tid >> 6, lane = tid & 63;
  const int wo = wave >> 1, wn = wave & 1;
  const int lrow = lane & 15, lgq = lane >> 4;
  const int xc = tid >> 2, xq = tid & 3;              // X staging map
  const int gslot = lane & 7;

  const _Float16* Grow = GmH + (size_t)(b * kC + ot * 128) * kC;

  // G tile: async global->LDS, source pre-swizzled with f(r)=(r^(r>>3))&7
  auto issueG = [&](int cc) {
#pragma unroll
    for (int rep = 0; rep < 4; ++rep) {
      const int rr = rep * 32 + wave * 8 + (lane >> 3);
      const int g = gslot ^ ((rr ^ (rr >> 3)) & 7);
      gload16(Grow + (size_t)rr * kC + cc + g * 8,
              (char*)GT + (rep * 32 + wave * 8) * 128);   // wave-uniform dest
    }
  };
  // X tile: global->VGPR (prefetchable), then transposed scalar LDS writes
  uint4 xr[4];
  auto loadX = [&](int cc) {
    const _Float16* xp = xH + ((size_t)b * kC + cc + xc) * kHW + nt * 128;
#pragma unroll
    for (int rep = 0; rep < 4; ++rep)
      xr[rep] = *(const uint4*)(xp + rep * 32 + xq * 8);
  };
  auto writeX = [&]() {
#pragma unroll
    for (int rep = 0; rep < 4; ++rep) {
      const int n0 = rep * 32 + xq * 8;
      V8 hx; hx.u = xr[rep];
#pragma unroll
      for (int k = 0; k < 8; ++k) {
        const int n = n0 + k;
        *(_Float16*)((char*)XT + (size_t)n * 128 +
                     (((unsigned)((xc >> 3) ^ ((n ^ (n >> 3)) & 7))) << 4) +
                     (xc & 7) * 2) = hx.h[k];
      }
    }
  };

  f32x4 acc[16];
#pragma unroll
  for (int i = 0; i < 16; ++i) acc[i] = (f32x4){0.f, 0.f, 0.f, 0.f};

  // prologue: chunk 0
  issueG(0);
  loadX(0);
  writeX();
  __syncthreads();   // drains gload vmcnt + ds_writes: chunk 0 ready

  for (int ci = 0; ci < 4; ++ci) {
    if (ci < 3) loadX((ci + 1) * 64);   // X prefetch in flight under MFMA
#pragma unroll
    for (int sub = 0; sub < 2; ++sub) {
      const int gq = sub * 4 + lgq;
      f16x8 afr[4], bfr[4];
#pragma unroll
      for (int ia = 0; ia < 4; ++ia) {
        const int r = wo * 64 + ia * 16 + lrow;
        afr[ia] = *(const f16x8*)((const char*)GT + (size_t)r * 128 +
                                  (((unsigned)(gq ^ ((r ^ (r >> 3)) & 7))) << 4));
      }
#pragma unroll
      for (int jb = 0; jb < 4; ++jb) {
        const int r = wn * 64 + jb * 16 + lrow;
        bfr[jb] = *(const f16x8*)((const char*)XT + (size_t)r * 128 +
                                  (((unsigned)(gq ^ ((r ^ (r >> 3)) & 7))) << 4));
      }
#pragma unroll
      for (int ia = 0; ia < 4; ++ia)
#pragma unroll
        for (int jb = 0; jb < 4; ++jb)
          acc[ia * 4 + jb] = __builtin_amdgcn_mfma_f32_16x16x32_f16(afr[ia], bfr[jb], acc[ia * 4 + jb], 0, 0, 0);
    }
    __syncthreads();                    // all LDS reads of this chunk done
    if (ci < 3) {
      issueG((ci + 1) * 64);            // async refill of G region
      writeX();                         // transpose-write prefetched X
      __syncthreads();                  // drains gload + ds_writes
    }
  }
  // Coalesced epilogue: two o-half passes through LDS.
#pragma unroll
  for (int p = 0; p < 2; ++p) {
    if (wo == p) {
#pragma unroll
      for (int ia = 0; ia < 4; ++ia)
#pragma unroll
        for (int jb = 0; jb < 4; ++jb)
#pragma unroll
          for (int reg = 0; reg < 4; ++reg)
            Ep[(size_t)(ia * 16 + lgq * 4 + reg) * 132 + wn * 64 + jb * 16 + lrow] =
                acc[ia * 4 + jb][reg];
    }
    __syncthreads();
#pragma unroll
    for (int it = 0; it < 8; ++it) {
      const int id = it * 256 + tid;
      const int row = id >> 5, nc = (id & 31) * 4;
      const int o = ot * 128 + p * 64 + row;
      const float gvv = gvec[b * kC + o] + out_b[o];
      float4 e = *(const float4*)&Ep[(size_t)row * 132 + nc];
      const size_t gidx = ((size_t)b * kC + o) * kHW + nt * 128 + nc;
      float4 sk = *(const float4*)&x[gidx];
      float4 res = {e.x + gvv + sk.x, e.y + gvv + sk.y, e.z + gvv + sk.z, e.w + gvv + sk.w};
      *(float4*)&out[gidx] = res;
    }
    __syncthreads();
  }
}

extern "C" void kernel_launch(void* const* d_in, const int* in_sizes, int n_in,
                              void* d_out, int out_size, void* d_ws, size_t ws_size,
                              hipStream_t stream) {
  const float* x    = (const float*)d_in[0];
  const float* gnw  = (const float*)d_in[1];
  const float* gnb  = (const float*)d_in[2];
  const float* qkvw = (const float*)d_in[3];
  const float* qkvb = (const float*)d_in[4];
  const float* outw = (const float*)d_in[5];
  const float* outb = (const float*)d_in[6];
  float* out = (float*)d_out;
  float* ws = (float*)d_ws;

  _Float16* xH   = (_Float16*)(ws + oXH);
  float* Spart   = ws + oSpart;
  float* S       = ws + oS;
  float* sums    = ws + oSums;
  float* gv      = ws + oGv;
  float* score   = ws + oScore;
  _Float16* GmH  = (_Float16*)(ws + oGmH);

  // sums + gvec adjacent: one memset covers both
  hipMemsetAsync(sums, 0, (size_t)2 * kB * kC * sizeof(float), stream);
  k0_cast<<<dim3(4, kC, kB), 256, 0, stream>>>(x, xH, sums);
  k1_syrk<<<dim3(3 * kNSplit, kB), 256, 0, stream>>>(xH, Spart);
  k1r_reduce<<<dim3(3 * kB * 32), 256, 0, stream>>>(Spart, S);
  k3ab<<<dim3(kHeads, kB), 256, 0, stream>>>(S, sums, gnw, gnb, qkvw, qkvb, score);
  k5b_gemm<<<dim3(5, 4, kB), 256, 0, stream>>>(outw, S, sums, gnw, gnb, score,
                                               qkvw, qkvb, GmH, gv);
  k6_final<<<dim3(kHW / 128, kC / 128, kB), 256, 0, stream>>>(xH, GmH, gv, outb, x, out);
}

// Round 8
// 205.293 us; speedup vs baseline: 1.0618x; 1.0618x over previous
//
#include <hip/hip_runtime.h>

// ---------------------------------------------------------------------------
// Round 12: REVERT k6 to round-6/round-10 form (the 206.4us build).
//   Round-7's launch_bounds(256,4)+register-prefetch caused VGPR=64 scratch
//   spills (FETCH +21MB, WRITE +33MB). Synchronous G+X staging restored.
//   k0/k1/k1r/k3ab/k5b unchanged from the 206.4us build.
// ---------------------------------------------------------------------------

constexpr int kB = 4;
constexpr int kC = 256;
constexpr int kHW = 16384;
constexpr int kHeads = 64;
constexpr int kNG = 32;
constexpr int kCPG = 8;
constexpr int kCP1 = 257;
constexpr int kPS = 260;          // padded row stride (floats) for S
constexpr float kEPS = 1e-5f;
constexpr int kNSplit = 32;       // syrk K-splits

typedef __attribute__((ext_vector_type(8))) _Float16 f16x8;
typedef __attribute__((ext_vector_type(4))) _Float16 f16x4;
typedef __attribute__((ext_vector_type(4))) float f32x4;

union V8 { f16x8 v; uint4 u; _Float16 h[8]; };

// async global->LDS, 16B per lane; lds ptr must be wave-uniform.
__device__ __forceinline__ void gload16(const void* g, void* l) {
  __builtin_amdgcn_global_load_lds(
      (const __attribute__((address_space(1))) void*)g,
      (__attribute__((address_space(3))) void*)l, 16, 0, 0);
}

// workspace layout (float-unit offsets)
constexpr size_t oXH    = 0;                                    // fp16 xH [b][c][n]
constexpr size_t oSpart = oXH + (size_t)kB * kHW * kC / 2;      // 3*B*kNSplit*128*128
constexpr size_t oS     = oSpart + (size_t)3 * kB * kNSplit * 128 * 128;
constexpr size_t oSums  = oS + (size_t)kB * kCP1 * kPS;         // B x 256 row sums
constexpr size_t oGv    = oSums + (size_t)kB * kC;              // adjacent (one memset)
constexpr size_t oScore = oGv + (size_t)kB * kC;
constexpr size_t oGmH   = oScore + (size_t)kB * kHeads * 16;    // fp16 B x 256 x 256

// ---------------------------------------------------------------------------
// K0: streaming cast x -> xH (fp16, same layout) + fp32 row sums.
// ---------------------------------------------------------------------------
__global__ __launch_bounds__(256) void k0_cast(const float* __restrict__ x,
                                               _Float16* __restrict__ xH,
                                               float* __restrict__ sums) {
  const int seg = blockIdx.x, c = blockIdx.y, b = blockIdx.z;
  const int tid = threadIdx.x;
  const size_t base = ((size_t)b * kC + c) * kHW + (size_t)seg * 4096 + tid * 16;
  float4 v0 = *(const float4*)(x + base);
  float4 v1 = *(const float4*)(x + base + 4);
  float4 v2 = *(const float4*)(x + base + 8);
  float4 v3 = *(const float4*)(x + base + 12);
  V8 h0, h1;
  h0.h[0] = (_Float16)v0.x; h0.h[1] = (_Float16)v0.y;
  h0.h[2] = (_Float16)v0.z; h0.h[3] = (_Float16)v0.w;
  h0.h[4] = (_Float16)v1.x; h0.h[5] = (_Float16)v1.y;
  h0.h[6] = (_Float16)v1.z; h0.h[7] = (_Float16)v1.w;
  h1.h[0] = (_Float16)v2.x; h1.h[1] = (_Float16)v2.y;
  h1.h[2] = (_Float16)v2.z; h1.h[3] = (_Float16)v2.w;
  h1.h[4] = (_Float16)v3.x; h1.h[5] = (_Float16)v3.y;
  h1.h[6] = (_Float16)v3.z; h1.h[7] = (_Float16)v3.w;
  *(uint4*)(xH + base) = h0.u;
  *(uint4*)(xH + base + 8) = h1.u;
  float rs = (v0.x + v0.y + v0.z + v0.w) + (v1.x + v1.y + v1.z + v1.w) +
             (v2.x + v2.y + v2.z + v2.w) + (v3.x + v3.y + v3.z + v3.w);
#pragma unroll
  for (int off = 32; off; off >>= 1) rs += __shfl_xor(rs, off);
  __shared__ float ps[4];
  if ((tid & 63) == 0) ps[tid >> 6] = rs;
  __syncthreads();
  if (tid == 0) atomicAdd(&sums[b * kC + c], ps[0] + ps[1] + ps[2] + ps[3]);
}

// ---------------------------------------------------------------------------
// K1: MFMA syrk reading xH. Tiles (0,0),(0,1),(1,1) of 128x128; 32 K-splits.
// grid (96, B), 256 thr. XCD-pairing block remap.
// ---------------------------------------------------------------------------
__global__ __launch_bounds__(256) void k1_syrk(const _Float16* __restrict__ xH,
                                               float* __restrict__ Spart) {
  const int bx = blockIdx.x;
  const int chunk = bx / 24, rr0 = bx % 24;
  const int tt = rr0 >> 3;               // 0..2
  const int sp = chunk * 8 + (rr0 & 7);  // 0..31
  const int b = blockIdx.y;
  const int ti = (tt == 2) ? 1 : 0;
  const int tj = (tt == 0) ? 0 : 1;
  const bool diag = (ti == tj);
  const _Float16* xb = xH + (size_t)b * kC * kHW;
  const int n0 = sp * (kHW / kNSplit);   // 512 per split

  __shared__ __align__(16) _Float16 XI[2][128 * 64];   // 2 x 16 KB
  __shared__ __align__(16) _Float16 XJ[2][128 * 64];   // 2 x 16 KB

  const int tid = threadIdx.x;
  const int wave = tid >> 6, lane = tid & 63;
  const int wi = wave >> 1, wj = wave & 1;
  const int lrow = lane & 15, lgq = lane >> 4;
  const int srow = lane >> 3, sslot = lane & 7;

  const _Float16* srcI = xb + (size_t)(ti * 128) * kHW + n0;
  const _Float16* srcJ = xb + (size_t)(tj * 128) * kHW + n0;

  f32x4 acc[16];
#pragma unroll
  for (int i = 0; i < 16; ++i) acc[i] = (f32x4){0.f, 0.f, 0.f, 0.f};

  auto stage = [&](int buf, int nb) {
#pragma unroll
    for (int rep = 0; rep < 4; ++rep) {
      const int rr = rep * 32 + wave * 8 + srow;
      const int g = sslot ^ (rr & 7);
      char* dI = (char*)XI[buf] + (rep * 32 + wave * 8) * 128;   // wave-uniform
      gload16(srcI + (size_t)rr * kHW + nb + g * 8, dI);
      if (!diag) {
        char* dJ = (char*)XJ[buf] + (rep * 32 + wave * 8) * 128;
        gload16(srcJ + (size_t)rr * kHW + nb + g * 8, dJ);
      }
    }
  };

  stage(0, 0);
  __syncthreads();   // drains vmcnt(0): buf0 ready

  constexpr int NCH = kHW / kNSplit / 64;   // 8
  for (int ch = 0; ch < NCH; ++ch) {
    const int buf = ch & 1;
    if (ch + 1 < NCH) stage(buf ^ 1, (ch + 1) * 64);   // prefetch next chunk
    const _Float16* XIb = XI[buf];
    const _Float16* XBb = diag ? XI[buf] : XJ[buf];
#pragma unroll
    for (int sub = 0; sub < 2; ++sub) {
      const int gq = sub * 4 + lgq;
      f16x8 afr[4], bfr[4];
#pragma unroll
      for (int ia = 0; ia < 4; ++ia) {
        const int r = wi * 64 + ia * 16 + lrow;
        afr[ia] = *(const f16x8*)((const char*)XIb + (size_t)r * 128 + (((unsigned)(gq ^ (r & 7))) << 4));
      }
#pragma unroll
      for (int jb = 0; jb < 4; ++jb) {
        const int r = wj * 64 + jb * 16 + lrow;
        bfr[jb] = *(const f16x8*)((const char*)XBb + (size_t)r * 128 + (((unsigned)(gq ^ (r & 7))) << 4));
      }
#pragma unroll
      for (int ia = 0; ia < 4; ++ia)
#pragma unroll
        for (int jb = 0; jb < 4; ++jb)
          acc[ia * 4 + jb] = __builtin_amdgcn_mfma_f32_16x16x32_f16(afr[ia], bfr[jb], acc[ia * 4 + jb], 0, 0, 0);
    }
    __syncthreads();   // drains prefetch vmcnt + LDS reads; buf^1 ready
  }
  float* P = Spart + (((size_t)tt * kB + b) * kNSplit + sp) * 16384;
#pragma unroll
  for (int ia = 0; ia < 4; ++ia)
#pragma unroll
    for (int jb = 0; jb < 4; ++jb)
#pragma unroll
      for (int reg = 0; reg < 4; ++reg) {
        const int i = wi * 64 + ia * 16 + lgq * 4 + reg;
        const int j = wj * 64 + jb * 16 + lrow;
        P[(size_t)i * 128 + j] = acc[ia * 4 + jb][reg];
      }
}

// ---------------------------------------------------------------------------
// K1r: reduce split partials -> full symmetric padded S (stride kPS).
// ---------------------------------------------------------------------------
__global__ __launch_bounds__(256) void k1r_reduce(const float* __restrict__ Spart,
                                                  float* __restrict__ S) {
  const int blk = blockIdx.x;
  const int tile12 = blk >> 5;          // 0..11
  const int part = blk & 31;
  const int tt = tile12 >> 2, b = tile12 & 3;
  const int rti = (tt == 2) ? 1 : 0;
  const int rtj = (tt == 0) ? 0 : 1;
  const int e0 = part * 512 + threadIdx.x * 2;
  float2 s = {0.f, 0.f};
  const float* base = Spart + ((size_t)tt * kB + b) * kNSplit * 16384 + e0;
#pragma unroll 8
  for (int sp = 0; sp < kNSplit; ++sp) {
    float2 v = *(const float2*)(base + (size_t)sp * 16384);
    s.x += v.x; s.y += v.y;
  }
  const int i = e0 >> 7, j = e0 & 127;
  float* Sb = S + (size_t)b * kCP1 * kPS;
  float* dst = Sb + (size_t)(rti * 128 + i) * kPS + rtj * 128 + j;
  dst[0] = s.x; dst[1] = s.y;
  if (tt == 1) {  // mirror into lower triangle
    Sb[(size_t)(128 + j + 0) * kPS + i] = s.x;
    Sb[(size_t)(128 + j + 1) * kPS + i] = s.y;
  }
}

// ---------------------------------------------------------------------------
// K3ab: scores directly from S (fused k3a+k3b); GN stats inline.
// ---------------------------------------------------------------------------
__global__ __launch_bounds__(256) void k3ab(const float* __restrict__ S,
                                            const float* __restrict__ sums,
                                            const float* __restrict__ gw,
                                            const float* __restrict__ gb,
                                            const float* __restrict__ qkv_w,
                                            const float* __restrict__ qkv_b,
                                            float* __restrict__ score) {
  const int h = blockIdx.x, b = blockIdx.y;
  const float* Sb = S + (size_t)b * kCP1 * kPS;
  const float HWf = (float)kHW;
  __shared__ float shx[kC], shd[kC];
  __shared__ float meanv[kNG], invv[kNG];
  __shared__ float4 suw[kC];
  __shared__ float redPQ[4][8];
  __shared__ float red16[4][16];
  const int tid = threadIdx.x;
  const int wave = tid >> 6, lane = tid & 63;

  shx[tid] = sums[b * kC + tid];
  shd[tid] = Sb[(size_t)tid * kPS + tid];
  __syncthreads();
  if (tid < kNG) {
    float sum = 0.f, ssq = 0.f;
#pragma unroll
    for (int k = 0; k < kCPG; ++k) { sum += shx[tid * kCPG + k]; ssq += shd[tid * kCPG + k]; }
    const float n = (float)(kCPG * kHW);
    const float mean = sum / n;
    const float var = (ssq - n * mean * mean) / (n - 1.0f);  // ddof=1
    meanv[tid] = mean;
    invv[tid] = rsqrtf(var + kEPS);
  }
  __syncthreads();
  const float s_c = gw[tid] * invv[tid / kCPG];
  const float t_c = gb[tid] - meanv[tid / kCPG] * s_c;
  const float x_c = shx[tid];
  const float r_c = s_c * x_c + t_c * HWf;

  const float u0 = qkv_w[(size_t)(h * 12 + 0) * kC + tid];
  const float u1 = qkv_w[(size_t)(h * 12 + 1) * kC + tid];
  const float u2 = qkv_w[(size_t)(h * 12 + 2) * kC + tid];
  const float u3 = qkv_w[(size_t)(h * 12 + 3) * kC + tid];
  const float v0 = qkv_w[(size_t)(h * 12 + 4) * kC + tid];
  const float v1 = qkv_w[(size_t)(h * 12 + 5) * kC + tid];
  const float v2 = qkv_w[(size_t)(h * 12 + 6) * kC + tid];
  const float v3 = qkv_w[(size_t)(h * 12 + 7) * kC + tid];
  suw[tid] = make_float4(u0 * s_c, u1 * s_c, u2 * s_c, u3 * s_c);

  float p[8] = {u0 * s_c * x_c, u1 * s_c * x_c, u2 * s_c * x_c, u3 * s_c * x_c,
                u0 * t_c, u1 * t_c, u2 * t_c, u3 * t_c};
#pragma unroll
  for (int i = 0; i < 8; ++i)
#pragma unroll
    for (int off = 32; off; off >>= 1) p[i] += __shfl_xor(p[i], off);
  if (lane == 0) {
#pragma unroll
    for (int i = 0; i < 8; ++i) redPQ[wave][i] = p[i];
  }
  __syncthreads();
  float P[4], Qp[4];
#pragma unroll
  for (int d = 0; d < 4; ++d) {
    P[d]  = redPQ[0][d] + redPQ[1][d] + redPQ[2][d] + redPQ[3][d];
    Qp[d] = redPQ[0][4 + d] + redPQ[1][4 + d] + redPQ[2][4 + d] + redPQ[3][4 + d]
            + qkv_b[h * 12 + d];
  }

  float sd0 = 0.f, sd1 = 0.f, sd2 = 0.f, sd3 = 0.f;
#pragma unroll 8
  for (int c = 0; c < kC; ++c) {
    const float Sval = Sb[(size_t)c * kPS + tid];
    const float4 w = suw[c];
    sd0 += w.x * Sval; sd1 += w.y * Sval; sd2 += w.z * Sval; sd3 += w.w * Sval;
  }
  float wd[4];
#pragma unroll
  for (int d = 0; d < 4; ++d) {
    const float sdv = (d == 0) ? sd0 : (d == 1) ? sd1 : (d == 2) ? sd2 : sd3;
    wd[d] = s_c * sdv + t_c * P[d] + r_c * Qp[d];
  }
  const float sv[4] = {v0, v1, v2, v3};
  float pr[16];
#pragma unroll
  for (int d = 0; d < 4; ++d)
#pragma unroll
    for (int e = 0; e < 4; ++e) pr[d * 4 + e] = wd[d] * sv[e];
#pragma unroll
  for (int i = 0; i < 16; ++i)
#pragma unroll
    for (int off = 32; off; off >>= 1) pr[i] += __shfl_xor(pr[i], off);
  if (lane == 0) {
#pragma unroll
    for (int i = 0; i < 16; ++i) red16[wave][i] = pr[i];
  }
  __syncthreads();
  if (tid < 16) {
    const int d = tid >> 2, e = tid & 3;
    float tot = red16[0][tid] + red16[1][tid] + red16[2][tid] + red16[3][tid];
    const float w256 = P[d] + HWf * Qp[d];
    tot += w256 * qkv_b[h * 12 + 4 + e];
    score[((size_t)(b * kHeads) + h) * 16 + tid] = 0.5f * tot;
  }
}

// ---------------------------------------------------------------------------
// K5b (k45 fused): softmax over heads in-block, M synthesized during staging
// as rank-4 mix of Wv rows; F = out_w @ M'; emit G fp16 + gvec atomics.
// ---------------------------------------------------------------------------
__global__ __launch_bounds__(256) void k5b_gemm(const float* __restrict__ out_w,
                                                const float* __restrict__ S,
                                                const float* __restrict__ sums,
                                                const float* __restrict__ gw,
                                                const float* __restrict__ gb,
                                                const float* __restrict__ score,
                                                const float* __restrict__ qkv_w,
                                                const float* __restrict__ qkv_b,
                                                _Float16* __restrict__ GmH,
                                                float* __restrict__ gvec) {
  const int ct = blockIdx.x, ot = blockIdx.y, b = blockIdx.z;
  const float* Sb = S + (size_t)b * kCP1 * kPS;
  __shared__ float Wt[32][68];
  __shared__ float Gs[32][68];
  __shared__ float gred[64][17];
  __shared__ float sS[kC], sT[kC];
  __shared__ float meanv[kNG], invv[kNG];
  __shared__ float scs[kHeads * 16];     // 4 KB scores
  __shared__ float pw[kC][4];            // softmax weights per cidx
  __shared__ float mxp[16], smp[16];
  __shared__ float wred[4][16];
  const int tid = threadIdx.x;
  const int wave = tid >> 6, lane = tid & 63;

  sS[tid] = sums[b * kC + tid];
  sT[tid] = Sb[(size_t)tid * kPS + tid];        // diag (temp)
  *(float4*)&scs[tid * 4] = ((const float4*)(score + (size_t)b * kHeads * 16))[tid];
  __syncthreads();
  if (tid < kNG) {
    float sum = 0.f, ssq = 0.f;
#pragma unroll
    for (int k = 0; k < kCPG; ++k) { sum += sS[tid * kCPG + k]; ssq += sT[tid * kCPG + k]; }
    const float n = (float)(kCPG * kHW);
    const float mean = sum / n;
    const float var = (ssq - n * mean * mean) / (n - 1.0f);
    meanv[tid] = mean;
    invv[tid] = rsqrtf(var + kEPS);
  }
  {
    const int p = tid & 15, hh = tid >> 4;
    float m = scs[(hh * 4 + 0) * 16 + p];
#pragma unroll
    for (int k = 1; k < 4; ++k) m = fmaxf(m, scs[(hh * 4 + k) * 16 + p]);
    m = fmaxf(m, __shfl_xor(m, 16));
    m = fmaxf(m, __shfl_xor(m, 32));
    if (lane < 16) wred[wave][lane] = m;
  }
  __syncthreads();
  if (tid < 16) mxp[tid] = fmaxf(fmaxf(wred[0][tid], wred[1][tid]),
                                 fmaxf(wred[2][tid], wred[3][tid]));
  __syncthreads();
  {
    const int p = tid & 15, hh = tid >> 4;
    float s = 0.f;
#pragma unroll
    for (int k = 0; k < 4; ++k) s += expf(scs[(hh * 4 + k) * 16 + p] - mxp[p]);
    s += __shfl_xor(s, 16);
    s += __shfl_xor(s, 32);
    if (lane < 16) wred[wave][lane] = s;
  }
  __syncthreads();
  if (tid < 16) smp[tid] = wred[0][tid] + wred[1][tid] + wred[2][tid] + wred[3][tid];
  __syncthreads();
  {
    const int h = tid >> 2, d = tid & 3;
#pragma unroll
    for (int e = 0; e < 4; ++e)
      pw[tid][e] = expf(scs[h * 16 + d * 4 + e] - mxp[d * 4 + e]) / smp[d * 4 + e];
    const float sv = gw[tid] * invv[tid / kCPG];
    sS[tid] = sv;
    sT[tid] = gb[tid] - meanv[tid / kCPG] * sv;
  }
  __syncthreads();

  float acc[16];
#pragma unroll
  for (int i = 0; i < 16; ++i) acc[i] = 0.f;
  const int i0 = (tid & 15) * 4;
  const int j0 = (tid >> 4) * 4;
  const int cp0 = ct * 64;

  for (int cb = 0; cb < kC; cb += 32) {
    int idx = tid;
#pragma unroll
    for (int r = 0; r < 2; ++r) {
      const int m = idx >> 3;
      const int c4 = (idx & 7) * 4;
      float4 v = *(const float4*)(out_w + (size_t)(ot * 64 + m) * kC + cb + c4);
      Wt[c4 + 0][m] = v.x; Wt[c4 + 1][m] = v.y; Wt[c4 + 2][m] = v.z; Wt[c4 + 3][m] = v.w;
      idx += 256;
    }
    idx = tid;
#pragma unroll
    for (int r = 0; r < 2; ++r) {
      const int cc = idx >> 4;
      const int n4 = (idx & 15) * 4;
      const int cidx = cb + cc;
      const int h = cidx >> 2;
      const float4 pv = *(const float4*)&pw[cidx][0];
      const int cp = cp0 + n4;
      float4 o;
      if (cp < kC) {
        const float* w0 = qkv_w + (size_t)(h * 12 + 8) * kC + cp;
        const float4 a0 = *(const float4*)(w0);
        const float4 a1 = *(const float4*)(w0 + kC);
        const float4 a2 = *(const float4*)(w0 + 2 * kC);
        const float4 a3 = *(const float4*)(w0 + 3 * kC);
        o.x = pv.x * a0.x + pv.y * a1.x + pv.z * a2.x + pv.w * a3.x;
        o.y = pv.x * a0.y + pv.y * a1.y + pv.z * a2.y + pv.w * a3.y;
        o.z = pv.x * a0.z + pv.y * a1.z + pv.z * a2.z + pv.w * a3.z;
        o.w = pv.x * a0.w + pv.y * a1.w + pv.z * a2.w + pv.w * a3.w;
      } else if (cp == kC) {
        const float bs = pv.x * qkv_b[h * 12 + 8] + pv.y * qkv_b[h * 12 + 9] +
                         pv.z * qkv_b[h * 12 + 10] + pv.w * qkv_b[h * 12 + 11];
        o = (float4){bs, 0.f, 0.f, 0.f};
      } else {
        o = (float4){0.f, 0.f, 0.f, 0.f};
      }
      *(float4*)&Gs[cc][n4] = o;
      idx += 256;
    }
    __syncthreads();
#pragma unroll
    for (int kk = 0; kk < 32; ++kk) {
      float4 a = *(const float4*)&Wt[kk][i0];
      float4 g = *(const float4*)&Gs[kk][j0];
      acc[0]  += a.x * g.x; acc[1]  += a.x * g.y; acc[2]  += a.x * g.z; acc[3]  += a.x * g.w;
      acc[4]  += a.y * g.x; acc[5]  += a.y * g.y; acc[6]  += a.y * g.z; acc[7]  += a.y * g.w;
      acc[8]  += a.z * g.x; acc[9]  += a.z * g.y; acc[10] += a.z * g.z; acc[11] += a.z * g.w;
      acc[12] += a.w * g.x; acc[13] += a.w * g.y; acc[14] += a.w * g.z; acc[15] += a.w * g.w;
    }
    __syncthreads();
  }
  float gpart[4] = {0.f, 0.f, 0.f, 0.f};
#pragma unroll
  for (int mi = 0; mi < 4; ++mi) {
    const int o = ot * 64 + i0 + mi;
#pragma unroll
    for (int cj = 0; cj < 4; ++cj) {
      const int cp = cp0 + j0 + cj;
      const float f = acc[mi * 4 + cj];
      if (cp < kC) {
        GmH[((size_t)b * kC + o) * kC + cp] = (_Float16)(f * sS[cp]);
        gpart[mi] += f * sT[cp];
      } else if (cp == kC) {
        gpart[mi] += f;
      }
    }
  }
#pragma unroll
  for (int mi = 0; mi < 4; ++mi) gred[i0 + mi][tid >> 4] = gpart[mi];
  __syncthreads();
  if (tid < 64) {
    float s = 0.f;
#pragma unroll
    for (int k = 0; k < 16; ++k) s += gred[tid][k];
    atomicAdd(&gvec[b * kC + ot * 64 + tid], s);
  }
}

// ---------------------------------------------------------------------------
// K6: out = G @ X + (g + out_b) + skip via MFMA; coalesced LDS epilogue.
// Round-6 form: synchronous G vector-load staging + X in-LDS transpose.
// grid (HW/128, C/128, B), 256 thr.
// ---------------------------------------------------------------------------
__global__ __launch_bounds__(256) void k6_final(const _Float16* __restrict__ xH,
                                                const _Float16* __restrict__ GmH,
                                                const float* __restrict__ gvec,
                                                const float* __restrict__ out_b,
                                                const float* __restrict__ x,
                                                float* __restrict__ out) {
  const int nt = blockIdx.x, ot = blockIdx.y, b = blockIdx.z;
  __shared__ __align__(16) char smem[64 * 132 * 4];   // 33792 B; aliased below
  _Float16* GT = (_Float16*)smem;                     // 16 KB
  _Float16* XT = (_Float16*)(smem + 16384);           // 16 KB
  float* Ep = (float*)smem;                           // epilogue 64 x 132 fp32
  const int tid = threadIdx.x;
  const int wave = tid >> 6, lane = tid & 63;
  const int wo = wave >> 1, wn = wave & 1;
  const int lrow = lane & 15, lgq = lane >> 4;
  const int xc = tid >> 2, xq = tid & 3;              // X staging map

  f32x4 acc[16];
#pragma unroll
  for (int i = 0; i < 16; ++i) acc[i] = (f32x4){0.f, 0.f, 0.f, 0.f};

  for (int cc = 0; cc < kC; cc += 64) {
    // G stage: vector loads + swizzled 16B stores
#pragma unroll
    for (int rep = 0; rep < 4; ++rep) {
      const int gi = tid + rep * 256;
      const int r = gi >> 3, g = gi & 7;
      const size_t boff = (size_t)r * 128 + (((unsigned)(g ^ ((r ^ (r >> 3)) & 7))) << 4);
      uint4 gv = *(const uint4*)(GmH + ((size_t)(b * kC + ot * 128 + r)) * kC + cc + g * 8);
      *(uint4*)((char*)GT + boff) = gv;
    }
    // X stage: transpose xH[c][n] -> XT[n][c] (8 scalar fp16 stores / 16B load)
    {
      const _Float16* xrow = xH + ((size_t)b * kC + cc + xc) * kHW + nt * 128;
#pragma unroll
      for (int rep = 0; rep < 4; ++rep) {
        const int n0 = rep * 32 + xq * 8;
        V8 hx; hx.u = *(const uint4*)(xrow + n0);
#pragma unroll
        for (int k = 0; k < 8; ++k) {
          const int n = n0 + k;
          *(_Float16*)((char*)XT + (size_t)n * 128 +
                       (((unsigned)((xc >> 3) ^ ((n ^ (n >> 3)) & 7))) << 4) +
                       (xc & 7) * 2) = hx.h[k];
        }
      }
    }
    __syncthreads();
#pragma unroll
    for (int sub = 0; sub < 2; ++sub) {
      const int gq = sub * 4 + lgq;
      f16x8 afr[4], bfr[4];
#pragma unroll
      for (int ia = 0; ia < 4; ++ia) {
        const int r = wo * 64 + ia * 16 + lrow;
        afr[ia] = *(const f16x8*)((const char*)GT + (size_t)r * 128 +
                                  (((unsigned)(gq ^ ((r ^ (r >> 3)) & 7))) << 4));
      }
#pragma unroll
      for (int jb = 0; jb < 4; ++jb) {
        const int r = wn * 64 + jb * 16 + lrow;
        bfr[jb] = *(const f16x8*)((const char*)XT + (size_t)r * 128 +
                                  (((unsigned)(gq ^ ((r ^ (r >> 3)) & 7))) << 4));
      }
#pragma unroll
      for (int ia = 0; ia < 4; ++ia)
#pragma unroll
        for (int jb = 0; jb < 4; ++jb)
          acc[ia * 4 + jb] = __builtin_amdgcn_mfma_f32_16x16x32_f16(afr[ia], bfr[jb], acc[ia * 4 + jb], 0, 0, 0);
    }
    __syncthreads();
  }
  // Coalesced epilogue: two o-half passes through LDS.
#pragma unroll
  for (int p = 0; p < 2; ++p) {
    if (wo == p) {
#pragma unroll
      for (int ia = 0; ia < 4; ++ia)
#pragma unroll
        for (int jb = 0; jb < 4; ++jb)
#pragma unroll
          for (int reg = 0; reg < 4; ++reg)
            Ep[(size_t)(ia * 16 + lgq * 4 + reg) * 132 + wn * 64 + jb * 16 + lrow] =
                acc[ia * 4 + jb][reg];
    }
    __syncthreads();
#pragma unroll
    for (int it = 0; it < 8; ++it) {
      const int id = it * 256 + tid;
      const int row = id >> 5, nc = (id & 31) * 4;
      const int o = ot * 128 + p * 64 + row;
      const float gvv = gvec[b * kC + o] + out_b[o];
      float4 e = *(const float4*)&Ep[(size_t)row * 132 + nc];
      const size_t gidx = ((size_t)b * kC + o) * kHW + nt * 128 + nc;
      float4 sk = *(const float4*)&x[gidx];
      float4 res = {e.x + gvv + sk.x, e.y + gvv + sk.y, e.z + gvv + sk.z, e.w + gvv + sk.w};
      *(float4*)&out[gidx] = res;
    }
    __syncthreads();
  }
}

extern "C" void kernel_launch(void* const* d_in, const int* in_sizes, int n_in,
                              void* d_out, int out_size, void* d_ws, size_t ws_size,
                              hipStream_t stream) {
  const float* x    = (const float*)d_in[0];
  const float* gnw  = (const float*)d_in[1];
  const float* gnb  = (const float*)d_in[2];
  const float* qkvw = (const float*)d_in[3];
  const float* qkvb = (const float*)d_in[4];
  const float* outw = (const float*)d_in[5];
  const float* outb = (const float*)d_in[6];
  float* out = (float*)d_out;
  float* ws = (float*)d_ws;

  _Float16* xH   = (_Float16*)(ws + oXH);
  float* Spart   = ws + oSpart;
  float* S       = ws + oS;
  float* sums    = ws + oSums;
  float* gv      = ws + oGv;
  float* score   = ws + oScore;
  _Float16* GmH  = (_Float16*)(ws + oGmH);

  // sums + gvec adjacent: one memset covers both
  hipMemsetAsync(sums, 0, (size_t)2 * kB * kC * sizeof(float), stream);
  k0_cast<<<dim3(4, kC, kB), 256, 0, stream>>>(x, xH, sums);
  k1_syrk<<<dim3(3 * kNSplit, kB), 256, 0, stream>>>(xH, Spart);
  k1r_reduce<<<dim3(3 * kB * 32), 256, 0, stream>>>(Spart, S);
  k3ab<<<dim3(kHeads, kB), 256, 0, stream>>>(S, sums, gnw, gnb, qkvw, qkvb, score);
  k5b_gemm<<<dim3(5, 4, kB), 256, 0, stream>>>(outw, S, sums, gnw, gnb, score,
                                               qkvw, qkvb, GmH, gv);
  k6_final<<<dim3(kHW / 128, kC / 128, kB), 256, 0, stream>>>(xH, GmH, gv, outb, x, out);
}

// Round 9
// 201.127 us; speedup vs baseline: 1.0838x; 1.0207x over previous
//
#include <hip/hip_runtime.h>

// ---------------------------------------------------------------------------
// Round 13 (single change): k6 skip read from xH (fp16, L2-hot — same rows
// already staged) instead of fp32 x. Deletes k6's only cold HBM read stream
// (64 MB). Everything else identical to the 205.3us round-12 build.
// ---------------------------------------------------------------------------

constexpr int kB = 4;
constexpr int kC = 256;
constexpr int kHW = 16384;
constexpr int kHeads = 64;
constexpr int kNG = 32;
constexpr int kCPG = 8;
constexpr int kCP1 = 257;
constexpr int kPS = 260;          // padded row stride (floats) for S
constexpr float kEPS = 1e-5f;
constexpr int kNSplit = 32;       // syrk K-splits

typedef __attribute__((ext_vector_type(8))) _Float16 f16x8;
typedef __attribute__((ext_vector_type(4))) _Float16 f16x4;
typedef __attribute__((ext_vector_type(4))) float f32x4;

union V8 { f16x8 v; uint4 u; _Float16 h[8]; };

// async global->LDS, 16B per lane; lds ptr must be wave-uniform.
__device__ __forceinline__ void gload16(const void* g, void* l) {
  __builtin_amdgcn_global_load_lds(
      (const __attribute__((address_space(1))) void*)g,
      (__attribute__((address_space(3))) void*)l, 16, 0, 0);
}

// workspace layout (float-unit offsets)
constexpr size_t oXH    = 0;                                    // fp16 xH [b][c][n]
constexpr size_t oSpart = oXH + (size_t)kB * kHW * kC / 2;      // 3*B*kNSplit*128*128
constexpr size_t oS     = oSpart + (size_t)3 * kB * kNSplit * 128 * 128;
constexpr size_t oSums  = oS + (size_t)kB * kCP1 * kPS;         // B x 256 row sums
constexpr size_t oGv    = oSums + (size_t)kB * kC;              // adjacent (one memset)
constexpr size_t oScore = oGv + (size_t)kB * kC;
constexpr size_t oGmH   = oScore + (size_t)kB * kHeads * 16;    // fp16 B x 256 x 256

// ---------------------------------------------------------------------------
// K0: streaming cast x -> xH (fp16, same layout) + fp32 row sums.
// ---------------------------------------------------------------------------
__global__ __launch_bounds__(256) void k0_cast(const float* __restrict__ x,
                                               _Float16* __restrict__ xH,
                                               float* __restrict__ sums) {
  const int seg = blockIdx.x, c = blockIdx.y, b = blockIdx.z;
  const int tid = threadIdx.x;
  const size_t base = ((size_t)b * kC + c) * kHW + (size_t)seg * 4096 + tid * 16;
  float4 v0 = *(const float4*)(x + base);
  float4 v1 = *(const float4*)(x + base + 4);
  float4 v2 = *(const float4*)(x + base + 8);
  float4 v3 = *(const float4*)(x + base + 12);
  V8 h0, h1;
  h0.h[0] = (_Float16)v0.x; h0.h[1] = (_Float16)v0.y;
  h0.h[2] = (_Float16)v0.z; h0.h[3] = (_Float16)v0.w;
  h0.h[4] = (_Float16)v1.x; h0.h[5] = (_Float16)v1.y;
  h0.h[6] = (_Float16)v1.z; h0.h[7] = (_Float16)v1.w;
  h1.h[0] = (_Float16)v2.x; h1.h[1] = (_Float16)v2.y;
  h1.h[2] = (_Float16)v2.z; h1.h[3] = (_Float16)v2.w;
  h1.h[4] = (_Float16)v3.x; h1.h[5] = (_Float16)v3.y;
  h1.h[6] = (_Float16)v3.z; h1.h[7] = (_Float16)v3.w;
  *(uint4*)(xH + base) = h0.u;
  *(uint4*)(xH + base + 8) = h1.u;
  float rs = (v0.x + v0.y + v0.z + v0.w) + (v1.x + v1.y + v1.z + v1.w) +
             (v2.x + v2.y + v2.z + v2.w) + (v3.x + v3.y + v3.z + v3.w);
#pragma unroll
  for (int off = 32; off; off >>= 1) rs += __shfl_xor(rs, off);
  __shared__ float ps[4];
  if ((tid & 63) == 0) ps[tid >> 6] = rs;
  __syncthreads();
  if (tid == 0) atomicAdd(&sums[b * kC + c], ps[0] + ps[1] + ps[2] + ps[3]);
}

// ---------------------------------------------------------------------------
// K1: MFMA syrk reading xH. Tiles (0,0),(0,1),(1,1) of 128x128; 32 K-splits.
// grid (96, B), 256 thr. XCD-pairing block remap.
// ---------------------------------------------------------------------------
__global__ __launch_bounds__(256) void k1_syrk(const _Float16* __restrict__ xH,
                                               float* __restrict__ Spart) {
  const int bx = blockIdx.x;
  const int chunk = bx / 24, rr0 = bx % 24;
  const int tt = rr0 >> 3;               // 0..2
  const int sp = chunk * 8 + (rr0 & 7);  // 0..31
  const int b = blockIdx.y;
  const int ti = (tt == 2) ? 1 : 0;
  const int tj = (tt == 0) ? 0 : 1;
  const bool diag = (ti == tj);
  const _Float16* xb = xH + (size_t)b * kC * kHW;
  const int n0 = sp * (kHW / kNSplit);   // 512 per split

  __shared__ __align__(16) _Float16 XI[2][128 * 64];   // 2 x 16 KB
  __shared__ __align__(16) _Float16 XJ[2][128 * 64];   // 2 x 16 KB

  const int tid = threadIdx.x;
  const int wave = tid >> 6, lane = tid & 63;
  const int wi = wave >> 1, wj = wave & 1;
  const int lrow = lane & 15, lgq = lane >> 4;
  const int srow = lane >> 3, sslot = lane & 7;

  const _Float16* srcI = xb + (size_t)(ti * 128) * kHW + n0;
  const _Float16* srcJ = xb + (size_t)(tj * 128) * kHW + n0;

  f32x4 acc[16];
#pragma unroll
  for (int i = 0; i < 16; ++i) acc[i] = (f32x4){0.f, 0.f, 0.f, 0.f};

  auto stage = [&](int buf, int nb) {
#pragma unroll
    for (int rep = 0; rep < 4; ++rep) {
      const int rr = rep * 32 + wave * 8 + srow;
      const int g = sslot ^ (rr & 7);
      char* dI = (char*)XI[buf] + (rep * 32 + wave * 8) * 128;   // wave-uniform
      gload16(srcI + (size_t)rr * kHW + nb + g * 8, dI);
      if (!diag) {
        char* dJ = (char*)XJ[buf] + (rep * 32 + wave * 8) * 128;
        gload16(srcJ + (size_t)rr * kHW + nb + g * 8, dJ);
      }
    }
  };

  stage(0, 0);
  __syncthreads();   // drains vmcnt(0): buf0 ready

  constexpr int NCH = kHW / kNSplit / 64;   // 8
  for (int ch = 0; ch < NCH; ++ch) {
    const int buf = ch & 1;
    if (ch + 1 < NCH) stage(buf ^ 1, (ch + 1) * 64);   // prefetch next chunk
    const _Float16* XIb = XI[buf];
    const _Float16* XBb = diag ? XI[buf] : XJ[buf];
#pragma unroll
    for (int sub = 0; sub < 2; ++sub) {
      const int gq = sub * 4 + lgq;
      f16x8 afr[4], bfr[4];
#pragma unroll
      for (int ia = 0; ia < 4; ++ia) {
        const int r = wi * 64 + ia * 16 + lrow;
        afr[ia] = *(const f16x8*)((const char*)XIb + (size_t)r * 128 + (((unsigned)(gq ^ (r & 7))) << 4));
      }
#pragma unroll
      for (int jb = 0; jb < 4; ++jb) {
        const int r = wj * 64 + jb * 16 + lrow;
        bfr[jb] = *(const f16x8*)((const char*)XBb + (size_t)r * 128 + (((unsigned)(gq ^ (r & 7))) << 4));
      }
#pragma unroll
      for (int ia = 0; ia < 4; ++ia)
#pragma unroll
        for (int jb = 0; jb < 4; ++jb)
          acc[ia * 4 + jb] = __builtin_amdgcn_mfma_f32_16x16x32_f16(afr[ia], bfr[jb], acc[ia * 4 + jb], 0, 0, 0);
    }
    __syncthreads();   // drains prefetch vmcnt + LDS reads; buf^1 ready
  }
  float* P = Spart + (((size_t)tt * kB + b) * kNSplit + sp) * 16384;
#pragma unroll
  for (int ia = 0; ia < 4; ++ia)
#pragma unroll
    for (int jb = 0; jb < 4; ++jb)
#pragma unroll
      for (int reg = 0; reg < 4; ++reg) {
        const int i = wi * 64 + ia * 16 + lgq * 4 + reg;
        const int j = wj * 64 + jb * 16 + lrow;
        P[(size_t)i * 128 + j] = acc[ia * 4 + jb][reg];
      }
}

// ---------------------------------------------------------------------------
// K1r: reduce split partials -> full symmetric padded S (stride kPS).
// ---------------------------------------------------------------------------
__global__ __launch_bounds__(256) void k1r_reduce(const float* __restrict__ Spart,
                                                  float* __restrict__ S) {
  const int blk = blockIdx.x;
  const int tile12 = blk >> 5;          // 0..11
  const int part = blk & 31;
  const int tt = tile12 >> 2, b = tile12 & 3;
  const int rti = (tt == 2) ? 1 : 0;
  const int rtj = (tt == 0) ? 0 : 1;
  const int e0 = part * 512 + threadIdx.x * 2;
  float2 s = {0.f, 0.f};
  const float* base = Spart + ((size_t)tt * kB + b) * kNSplit * 16384 + e0;
#pragma unroll 8
  for (int sp = 0; sp < kNSplit; ++sp) {
    float2 v = *(const float2*)(base + (size_t)sp * 16384);
    s.x += v.x; s.y += v.y;
  }
  const int i = e0 >> 7, j = e0 & 127;
  float* Sb = S + (size_t)b * kCP1 * kPS;
  float* dst = Sb + (size_t)(rti * 128 + i) * kPS + rtj * 128 + j;
  dst[0] = s.x; dst[1] = s.y;
  if (tt == 1) {  // mirror into lower triangle
    Sb[(size_t)(128 + j + 0) * kPS + i] = s.x;
    Sb[(size_t)(128 + j + 1) * kPS + i] = s.y;
  }
}

// ---------------------------------------------------------------------------
// K3ab: scores directly from S (fused k3a+k3b); GN stats inline.
// ---------------------------------------------------------------------------
__global__ __launch_bounds__(256) void k3ab(const float* __restrict__ S,
                                            const float* __restrict__ sums,
                                            const float* __restrict__ gw,
                                            const float* __restrict__ gb,
                                            const float* __restrict__ qkv_w,
                                            const float* __restrict__ qkv_b,
                                            float* __restrict__ score) {
  const int h = blockIdx.x, b = blockIdx.y;
  const float* Sb = S + (size_t)b * kCP1 * kPS;
  const float HWf = (float)kHW;
  __shared__ float shx[kC], shd[kC];
  __shared__ float meanv[kNG], invv[kNG];
  __shared__ float4 suw[kC];
  __shared__ float redPQ[4][8];
  __shared__ float red16[4][16];
  const int tid = threadIdx.x;
  const int wave = tid >> 6, lane = tid & 63;

  shx[tid] = sums[b * kC + tid];
  shd[tid] = Sb[(size_t)tid * kPS + tid];
  __syncthreads();
  if (tid < kNG) {
    float sum = 0.f, ssq = 0.f;
#pragma unroll
    for (int k = 0; k < kCPG; ++k) { sum += shx[tid * kCPG + k]; ssq += shd[tid * kCPG + k]; }
    const float n = (float)(kCPG * kHW);
    const float mean = sum / n;
    const float var = (ssq - n * mean * mean) / (n - 1.0f);  // ddof=1
    meanv[tid] = mean;
    invv[tid] = rsqrtf(var + kEPS);
  }
  __syncthreads();
  const float s_c = gw[tid] * invv[tid / kCPG];
  const float t_c = gb[tid] - meanv[tid / kCPG] * s_c;
  const float x_c = shx[tid];
  const float r_c = s_c * x_c + t_c * HWf;

  const float u0 = qkv_w[(size_t)(h * 12 + 0) * kC + tid];
  const float u1 = qkv_w[(size_t)(h * 12 + 1) * kC + tid];
  const float u2 = qkv_w[(size_t)(h * 12 + 2) * kC + tid];
  const float u3 = qkv_w[(size_t)(h * 12 + 3) * kC + tid];
  const float v0 = qkv_w[(size_t)(h * 12 + 4) * kC + tid];
  const float v1 = qkv_w[(size_t)(h * 12 + 5) * kC + tid];
  const float v2 = qkv_w[(size_t)(h * 12 + 6) * kC + tid];
  const float v3 = qkv_w[(size_t)(h * 12 + 7) * kC + tid];
  suw[tid] = make_float4(u0 * s_c, u1 * s_c, u2 * s_c, u3 * s_c);

  float p[8] = {u0 * s_c * x_c, u1 * s_c * x_c, u2 * s_c * x_c, u3 * s_c * x_c,
                u0 * t_c, u1 * t_c, u2 * t_c, u3 * t_c};
#pragma unroll
  for (int i = 0; i < 8; ++i)
#pragma unroll
    for (int off = 32; off; off >>= 1) p[i] += __shfl_xor(p[i], off);
  if (lane == 0) {
#pragma unroll
    for (int i = 0; i < 8; ++i) redPQ[wave][i] = p[i];
  }
  __syncthreads();
  float P[4], Qp[4];
#pragma unroll
  for (int d = 0; d < 4; ++d) {
    P[d]  = redPQ[0][d] + redPQ[1][d] + redPQ[2][d] + redPQ[3][d];
    Qp[d] = redPQ[0][4 + d] + redPQ[1][4 + d] + redPQ[2][4 + d] + redPQ[3][4 + d]
            + qkv_b[h * 12 + d];
  }

  float sd0 = 0.f, sd1 = 0.f, sd2 = 0.f, sd3 = 0.f;
#pragma unroll 8
  for (int c = 0; c < kC; ++c) {
    const float Sval = Sb[(size_t)c * kPS + tid];
    const float4 w = suw[c];
    sd0 += w.x * Sval; sd1 += w.y * Sval; sd2 += w.z * Sval; sd3 += w.w * Sval;
  }
  float wd[4];
#pragma unroll
  for (int d = 0; d < 4; ++d) {
    const float sdv = (d == 0) ? sd0 : (d == 1) ? sd1 : (d == 2) ? sd2 : sd3;
    wd[d] = s_c * sdv + t_c * P[d] + r_c * Qp[d];
  }
  const float sv[4] = {v0, v1, v2, v3};
  float pr[16];
#pragma unroll
  for (int d = 0; d < 4; ++d)
#pragma unroll
    for (int e = 0; e < 4; ++e) pr[d * 4 + e] = wd[d] * sv[e];
#pragma unroll
  for (int i = 0; i < 16; ++i)
#pragma unroll
    for (int off = 32; off; off >>= 1) pr[i] += __shfl_xor(pr[i], off);
  if (lane == 0) {
#pragma unroll
    for (int i = 0; i < 16; ++i) red16[wave][i] = pr[i];
  }
  __syncthreads();
  if (tid < 16) {
    const int d = tid >> 2, e = tid & 3;
    float tot = red16[0][tid] + red16[1][tid] + red16[2][tid] + red16[3][tid];
    const float w256 = P[d] + HWf * Qp[d];
    tot += w256 * qkv_b[h * 12 + 4 + e];
    score[((size_t)(b * kHeads) + h) * 16 + tid] = 0.5f * tot;
  }
}

// ---------------------------------------------------------------------------
// K5b (k45 fused): softmax over heads in-block, M synthesized during staging
// as rank-4 mix of Wv rows; F = out_w @ M'; emit G fp16 + gvec atomics.
// ---------------------------------------------------------------------------
__global__ __launch_bounds__(256) void k5b_gemm(const float* __restrict__ out_w,
                                                const float* __restrict__ S,
                                                const float* __restrict__ sums,
                                                const float* __restrict__ gw,
                                                const float* __restrict__ gb,
                                                const float* __restrict__ score,
                                                const float* __restrict__ qkv_w,
                                                const float* __restrict__ qkv_b,
                                                _Float16* __restrict__ GmH,
                                                float* __restrict__ gvec) {
  const int ct = blockIdx.x, ot = blockIdx.y, b = blockIdx.z;
  const float* Sb = S + (size_t)b * kCP1 * kPS;
  __shared__ float Wt[32][68];
  __shared__ float Gs[32][68];
  __shared__ float gred[64][17];
  __shared__ float sS[kC], sT[kC];
  __shared__ float meanv[kNG], invv[kNG];
  __shared__ float scs[kHeads * 16];     // 4 KB scores
  __shared__ float pw[kC][4];            // softmax weights per cidx
  __shared__ float mxp[16], smp[16];
  __shared__ float wred[4][16];
  const int tid = threadIdx.x;
  const int wave = tid >> 6, lane = tid & 63;

  sS[tid] = sums[b * kC + tid];
  sT[tid] = Sb[(size_t)tid * kPS + tid];        // diag (temp)
  *(float4*)&scs[tid * 4] = ((const float4*)(score + (size_t)b * kHeads * 16))[tid];
  __syncthreads();
  if (tid < kNG) {
    float sum = 0.f, ssq = 0.f;
#pragma unroll
    for (int k = 0; k < kCPG; ++k) { sum += sS[tid * kCPG + k]; ssq += sT[tid * kCPG + k]; }
    const float n = (float)(kCPG * kHW);
    const float mean = sum / n;
    const float var = (ssq - n * mean * mean) / (n - 1.0f);
    meanv[tid] = mean;
    invv[tid] = rsqrtf(var + kEPS);
  }
  {
    const int p = tid & 15, hh = tid >> 4;
    float m = scs[(hh * 4 + 0) * 16 + p];
#pragma unroll
    for (int k = 1; k < 4; ++k) m = fmaxf(m, scs[(hh * 4 + k) * 16 + p]);
    m = fmaxf(m, __shfl_xor(m, 16));
    m = fmaxf(m, __shfl_xor(m, 32));
    if (lane < 16) wred[wave][lane] = m;
  }
  __syncthreads();
  if (tid < 16) mxp[tid] = fmaxf(fmaxf(wred[0][tid], wred[1][tid]),
                                 fmaxf(wred[2][tid], wred[3][tid]));
  __syncthreads();
  {
    const int p = tid & 15, hh = tid >> 4;
    float s = 0.f;
#pragma unroll
    for (int k = 0; k < 4; ++k) s += expf(scs[(hh * 4 + k) * 16 + p] - mxp[p]);
    s += __shfl_xor(s, 16);
    s += __shfl_xor(s, 32);
    if (lane < 16) wred[wave][lane] = s;
  }
  __syncthreads();
  if (tid < 16) smp[tid] = wred[0][tid] + wred[1][tid] + wred[2][tid] + wred[3][tid];
  __syncthreads();
  {
    const int h = tid >> 2, d = tid & 3;
#pragma unroll
    for (int e = 0; e < 4; ++e)
      pw[tid][e] = expf(scs[h * 16 + d * 4 + e] - mxp[d * 4 + e]) / smp[d * 4 + e];
    const float sv = gw[tid] * invv[tid / kCPG];
    sS[tid] = sv;
    sT[tid] = gb[tid] - meanv[tid / kCPG] * sv;
  }
  __syncthreads();

  float acc[16];
#pragma unroll
  for (int i = 0; i < 16; ++i) acc[i] = 0.f;
  const int i0 = (tid & 15) * 4;
  const int j0 = (tid >> 4) * 4;
  const int cp0 = ct * 64;

  for (int cb = 0; cb < kC; cb += 32) {
    int idx = tid;
#pragma unroll
    for (int r = 0; r < 2; ++r) {
      const int m = idx >> 3;
      const int c4 = (idx & 7) * 4;
      float4 v = *(const float4*)(out_w + (size_t)(ot * 64 + m) * kC + cb + c4);
      Wt[c4 + 0][m] = v.x; Wt[c4 + 1][m] = v.y; Wt[c4 + 2][m] = v.z; Wt[c4 + 3][m] = v.w;
      idx += 256;
    }
    idx = tid;
#pragma unroll
    for (int r = 0; r < 2; ++r) {
      const int cc = idx >> 4;
      const int n4 = (idx & 15) * 4;
      const int cidx = cb + cc;
      const int h = cidx >> 2;
      const float4 pv = *(const float4*)&pw[cidx][0];
      const int cp = cp0 + n4;
      float4 o;
      if (cp < kC) {
        const float* w0 = qkv_w + (size_t)(h * 12 + 8) * kC + cp;
        const float4 a0 = *(const float4*)(w0);
        const float4 a1 = *(const float4*)(w0 + kC);
        const float4 a2 = *(const float4*)(w0 + 2 * kC);
        const float4 a3 = *(const float4*)(w0 + 3 * kC);
        o.x = pv.x * a0.x + pv.y * a1.x + pv.z * a2.x + pv.w * a3.x;
        o.y = pv.x * a0.y + pv.y * a1.y + pv.z * a2.y + pv.w * a3.y;
        o.z = pv.x * a0.z + pv.y * a1.z + pv.z * a2.z + pv.w * a3.z;
        o.w = pv.x * a0.w + pv.y * a1.w + pv.z * a2.w + pv.w * a3.w;
      } else if (cp == kC) {
        const float bs = pv.x * qkv_b[h * 12 + 8] + pv.y * qkv_b[h * 12 + 9] +
                         pv.z * qkv_b[h * 12 + 10] + pv.w * qkv_b[h * 12 + 11];
        o = (float4){bs, 0.f, 0.f, 0.f};
      } else {
        o = (float4){0.f, 0.f, 0.f, 0.f};
      }
      *(float4*)&Gs[cc][n4] = o;
      idx += 256;
    }
    __syncthreads();
#pragma unroll
    for (int kk = 0; kk < 32; ++kk) {
      float4 a = *(const float4*)&Wt[kk][i0];
      float4 g = *(const float4*)&Gs[kk][j0];
      acc[0]  += a.x * g.x; acc[1]  += a.x * g.y; acc[2]  += a.x * g.z; acc[3]  += a.x * g.w;
      acc[4]  += a.y * g.x; acc[5]  += a.y * g.y; acc[6]  += a.y * g.z; acc[7]  += a.y * g.w;
      acc[8]  += a.z * g.x; acc[9]  += a.z * g.y; acc[10] += a.z * g.z; acc[11] += a.z * g.w;
      acc[12] += a.w * g.x; acc[13] += a.w * g.y; acc[14] += a.w * g.z; acc[15] += a.w * g.w;
    }
    __syncthreads();
  }
  float gpart[4] = {0.f, 0.f, 0.f, 0.f};
#pragma unroll
  for (int mi = 0; mi < 4; ++mi) {
    const int o = ot * 64 + i0 + mi;
#pragma unroll
    for (int cj = 0; cj < 4; ++cj) {
      const int cp = cp0 + j0 + cj;
      const float f = acc[mi * 4 + cj];
      if (cp < kC) {
        GmH[((size_t)b * kC + o) * kC + cp] = (_Float16)(f * sS[cp]);
        gpart[mi] += f * sT[cp];
      } else if (cp == kC) {
        gpart[mi] += f;
      }
    }
  }
#pragma unroll
  for (int mi = 0; mi < 4; ++mi) gred[i0 + mi][tid >> 4] = gpart[mi];
  __syncthreads();
  if (tid < 64) {
    float s = 0.f;
#pragma unroll
    for (int k = 0; k < 16; ++k) s += gred[tid][k];
    atomicAdd(&gvec[b * kC + ot * 64 + tid], s);
  }
}

// ---------------------------------------------------------------------------
// K6: out = G @ X + (g + out_b) + skip via MFMA; coalesced LDS epilogue.
// Skip read from xH (fp16, L2-hot: same rows staged above) — the fp32 x
// stream is deleted. grid (HW/128, C/128, B), 256 thr.
// ---------------------------------------------------------------------------
__global__ __launch_bounds__(256) void k6_final(const _Float16* __restrict__ xH,
                                                const _Float16* __restrict__ GmH,
                                                const float* __restrict__ gvec,
                                                const float* __restrict__ out_b,
                                                float* __restrict__ out) {
  const int nt = blockIdx.x, ot = blockIdx.y, b = blockIdx.z;
  __shared__ __align__(16) char smem[64 * 132 * 4];   // 33792 B; aliased below
  _Float16* GT = (_Float16*)smem;                     // 16 KB
  _Float16* XT = (_Float16*)(smem + 16384);           // 16 KB
  float* Ep = (float*)smem;                           // epilogue 64 x 132 fp32
  const int tid = threadIdx.x;
  const int wave = tid >> 6, lane = tid & 63;
  const int wo = wave >> 1, wn = wave & 1;
  const int lrow = lane & 15, lgq = lane >> 4;
  const int xc = tid >> 2, xq = tid & 3;              // X staging map

  f32x4 acc[16];
#pragma unroll
  for (int i = 0; i < 16; ++i) acc[i] = (f32x4){0.f, 0.f, 0.f, 0.f};

  for (int cc = 0; cc < kC; cc += 64) {
    // G stage: vector loads + swizzled 16B stores
#pragma unroll
    for (int rep = 0; rep < 4; ++rep) {
      const int gi = tid + rep * 256;
      const int r = gi >> 3, g = gi & 7;
      const size_t boff = (size_t)r * 128 + (((unsigned)(g ^ ((r ^ (r >> 3)) & 7))) << 4);
      uint4 gv = *(const uint4*)(GmH + ((size_t)(b * kC + ot * 128 + r)) * kC + cc + g * 8);
      *(uint4*)((char*)GT + boff) = gv;
    }
    // X stage: transpose xH[c][n] -> XT[n][c] (8 scalar fp16 stores / 16B load)
    {
      const _Float16* xrow = xH + ((size_t)b * kC + cc + xc) * kHW + nt * 128;
#pragma unroll
      for (int rep = 0; rep < 4; ++rep) {
        const int n0 = rep * 32 + xq * 8;
        V8 hx; hx.u = *(const uint4*)(xrow + n0);
#pragma unroll
        for (int k = 0; k < 8; ++k) {
          const int n = n0 + k;
          *(_Float16*)((char*)XT + (size_t)n * 128 +
                       (((unsigned)((xc >> 3) ^ ((n ^ (n >> 3)) & 7))) << 4) +
                       (xc & 7) * 2) = hx.h[k];
        }
      }
    }
    __syncthreads();
#pragma unroll
    for (int sub = 0; sub < 2; ++sub) {
      const int gq = sub * 4 + lgq;
      f16x8 afr[4], bfr[4];
#pragma unroll
      for (int ia = 0; ia < 4; ++ia) {
        const int r = wo * 64 + ia * 16 + lrow;
        afr[ia] = *(const f16x8*)((const char*)GT + (size_t)r * 128 +
                                  (((unsigned)(gq ^ ((r ^ (r >> 3)) & 7))) << 4));
      }
#pragma unroll
      for (int jb = 0; jb < 4; ++jb) {
        const int r = wn * 64 + jb * 16 + lrow;
        bfr[jb] = *(const f16x8*)((const char*)XT + (size_t)r * 128 +
                                  (((unsigned)(gq ^ ((r ^ (r >> 3)) & 7))) << 4));
      }
#pragma unroll
      for (int ia = 0; ia < 4; ++ia)
#pragma unroll
        for (int jb = 0; jb < 4; ++jb)
          acc[ia * 4 + jb] = __builtin_amdgcn_mfma_f32_16x16x32_f16(afr[ia], bfr[jb], acc[ia * 4 + jb], 0, 0, 0);
    }
    __syncthreads();
  }
  // Coalesced epilogue: two o-half passes through LDS.
#pragma unroll
  for (int p = 0; p < 2; ++p) {
    if (wo == p) {
#pragma unroll
      for (int ia = 0; ia < 4; ++ia)
#pragma unroll
        for (int jb = 0; jb < 4; ++jb)
#pragma unroll
          for (int reg = 0; reg < 4; ++reg)
            Ep[(size_t)(ia * 16 + lgq * 4 + reg) * 132 + wn * 64 + jb * 16 + lrow] =
                acc[ia * 4 + jb][reg];
    }
    __syncthreads();
#pragma unroll
    for (int it = 0; it < 8; ++it) {
      const int id = it * 256 + tid;
      const int row = id >> 5, nc = (id & 31) * 4;
      const int o = ot * 128 + p * 64 + row;
      const float gvv = gvec[b * kC + o] + out_b[o];
      float4 e = *(const float4*)&Ep[(size_t)row * 132 + nc];
      const size_t gidx = ((size_t)b * kC + o) * kHW + nt * 128 + nc;
      f16x4 sk = *(const f16x4*)(xH + gidx);          // fp16 skip, L2-hot
      float4 res = {e.x + gvv + (float)sk[0], e.y + gvv + (float)sk[1],
                    e.z + gvv + (float)sk[2], e.w + gvv + (float)sk[3]};
      *(float4*)&out[gidx] = res;
    }
    __syncthreads();
  }
}

extern "C" void kernel_launch(void* const* d_in, const int* in_sizes, int n_in,
                              void* d_out, int out_size, void* d_ws, size_t ws_size,
                              hipStream_t stream) {
  const float* x    = (const float*)d_in[0];
  const float* gnw  = (const float*)d_in[1];
  const float* gnb  = (const float*)d_in[2];
  const float* qkvw = (const float*)d_in[3];
  const float* qkvb = (const float*)d_in[4];
  const float* outw = (const float*)d_in[5];
  const float* outb = (const float*)d_in[6];
  float* out = (float*)d_out;
  float* ws = (float*)d_ws;

  _Float16* xH   = (_Float16*)(ws + oXH);
  float* Spart   = ws + oSpart;
  float* S       = ws + oS;
  float* sums    = ws + oSums;
  float* gv      = ws + oGv;
  float* score   = ws + oScore;
  _Float16* GmH  = (_Float16*)(ws + oGmH);

  // sums + gvec adjacent: one memset covers both
  hipMemsetAsync(sums, 0, (size_t)2 * kB * kC * sizeof(float), stream);
  k0_cast<<<dim3(4, kC, kB), 256, 0, stream>>>(x, xH, sums);
  k1_syrk<<<dim3(3 * kNSplit, kB), 256, 0, stream>>>(xH, Spart);
  k1r_reduce<<<dim3(3 * kB * 32), 256, 0, stream>>>(Spart, S);
  k3ab<<<dim3(kHeads, kB), 256, 0, stream>>>(S, sums, gnw, gnb, qkvw, qkvb, score);
  k5b_gemm<<<dim3(5, 4, kB), 256, 0, stream>>>(outw, S, sums, gnw, gnb, score,
                                               qkvw, qkvb, GmH, gv);
  k6_final<<<dim3(kHW / 128, kC / 128, kB), 256, 0, stream>>>(xH, GmH, gv, outb, out);
}